// Round 1
// baseline (595.730 us; speedup 1.0000x reference)
//
#include <hip/hip_runtime.h>

// NeuralSpectralBlock1d on MI355X (gfx950)
// B=32, C=256, H=4096, PATCH=4, HEAD=8, DH=32, NT=4, NB=12
// Fused design (v2):
//   wconv_kernel: enc_w(512x256) ++ dec_w(256x256) -> bf16 Wb in d_ws,
//                 laid out in MFMA *fragment order*:
//                 block(m16,kt) = 1024B: [quad][fm][8 bf16], so a lane's
//                 A-frag is one coalesced 16B global load (L2-resident).
//   nsb_kernel:   grid 2048 = 32 b * 64 col-chunks; block 512 thr (8 waves)
//     stage:   X tile (256k x 64col) -> LDS bf16 transposed, ONCE; + QL; 1 barrier
//     phase 1: Y(768x64) = Wb @ X via mfma_f32_16x16x32_bf16, BARRIER-FREE
//              (A-frags straight from global Wb; B-frags from LDS)
//              wave w owns rows [w*96, w*96+96): acc[6][4] f32x4 (96 VGPRs)
//     phase 2: two halves of 32 cols (8 patches); wave <-> patch; attn1/attn2
//              now use ALL 64 lanes (half-waves split cols/channels, scores
//              exchanged via __shfl_xor(.,32)); E/D writes u32-pair-packed.
//
// LDS map (54016 B):
//   stage/GEMM: Bl [0,33792)     64 cols * 528 B (256 bf16 k + pad)
//   epilog:     E  [0,32896)     32 cols * 1028 B; (k,v) pair word, d+4h swizzle
//               D  [0,16896)     32 cols * 528 B  (written after attn1; E dead)
//               LT [32896,49792) 8 patches * 4 l * 528 B
//               QL [49792,54016) latent fp32, [h][l][33] padded

typedef __attribute__((ext_vector_type(8))) short short8;
typedef __attribute__((ext_vector_type(4))) float f32x4;

#define DOFF 0
#define LTOFF 32896
#define QLOFF 49792

__device__ __forceinline__ unsigned short f2bf(float f) {
  union { float f; unsigned int u; } c; c.f = f;
  unsigned int u = c.u + 0x7FFFu + ((c.u >> 16) & 1u);
  return (unsigned short)(u >> 16);
}
__device__ __forceinline__ float bf2f(unsigned short s) {
  union { unsigned int u; float f; } c; c.u = ((unsigned int)s) << 16;
  return c.f;
}
__device__ __forceinline__ unsigned int pack2bf(float lo, float hi) {
  return (unsigned int)f2bf(lo) | ((unsigned int)f2bf(hi) << 16);
}

// Wb fragment layout: element index = ((m16*8 + kt)*64 + quad*16 + fm)*8 + j
// source: W[row = m16*16 + fm][k = kt*32 + quad*8 + j]
__global__ void wconv_kernel(const float* __restrict__ enc_w,
                             const float* __restrict__ dec_w,
                             unsigned short* __restrict__ Wb) {
  const int g   = blockIdx.x * 256 + threadIdx.x;  // 96*256 = 24576 = 196608/8
  const int blk = g >> 6;        // m16*8 + kt
  const int lp  = g & 63;        // quad*16 + fm
  const int m16 = blk >> 3, kt = blk & 7;
  const int fm  = lp & 15, quad = lp >> 4;
  const int row = m16 * 16 + fm;
  const int k   = kt * 32 + quad * 8;
  const float* src = (row < 512) ? (enc_w + row * 256 + k)
                                 : (dec_w + (row - 512) * 256 + k);
  const float4 v0 = *(const float4*)(src);
  const float4 v1 = *(const float4*)(src + 4);
  ushort4 o0, o1;
  o0.x = f2bf(v0.x); o0.y = f2bf(v0.y); o0.z = f2bf(v0.z); o0.w = f2bf(v0.w);
  o1.x = f2bf(v1.x); o1.y = f2bf(v1.y); o1.z = f2bf(v1.z); o1.w = f2bf(v1.w);
  *(ushort4*)(Wb + g * 8)     = o0;
  *(ushort4*)(Wb + g * 8 + 4) = o1;
}

__global__ __launch_bounds__(512, 4) void nsb_kernel(
    const float* __restrict__ x,
    const float* __restrict__ weights,
    const float* __restrict__ latent,
    const float* __restrict__ enc_b,
    const float* __restrict__ dec_b,
    const unsigned short* __restrict__ Wb,
    float* __restrict__ out)
{
  __shared__ __attribute__((aligned(16))) unsigned char smem[54016];
  const int t    = threadIdx.x;
  const int wv   = t >> 6;       // wave 0..7
  const int lane = t & 63;
  const int fm   = lane & 15;    // mfma m/n index
  const int quad = lane >> 4;    // mfma k-group / row-quad
  const int bb   = blockIdx.x >> 6;          // batch
  const int h0   = (blockIdx.x & 63) << 6;   // column base in H

  f32x4 acc[6][4];
#pragma unroll
  for (int i = 0; i < 6; ++i)
#pragma unroll
    for (int j = 0; j < 4; ++j)
      acc[i][j] = f32x4{0.f, 0.f, 0.f, 0.f};

  // ---------------- stage: full X tile -> Bl (bf16, transposed) + QL ----------------
  {
    const int cB = t >> 4;          // 0..31
    const int h4 = (t & 15) << 2;   // 0..60
    const float* xb = x + (bb * 256 + cB) * 4096 + h0 + h4;
#pragma unroll
    for (int rd = 0; rd < 8; ++rd) {
      const float4 xv = *(const float4*)(xb + rd * 32 * 4096);
      const int c2 = (rd * 32 + cB) * 2;
      *(unsigned short*)(smem + (h4 + 0) * 528 + c2) = f2bf(xv.x);
      *(unsigned short*)(smem + (h4 + 1) * 528 + c2) = f2bf(xv.y);
      *(unsigned short*)(smem + (h4 + 2) * 528 + c2) = f2bf(xv.z);
      *(unsigned short*)(smem + (h4 + 3) * 528 + c2) = f2bf(xv.w);
    }
  }
  {
    const int e0 = t * 2;
    const float2 lv = *(const float2*)(latent + e0);
    int h_ = e0 >> 7, l_ = (e0 >> 5) & 3, d_ = e0 & 31;
    *(float*)(smem + QLOFF + (h_ * 132 + l_ * 33 + d_) * 4) = lv.x;
    const int e1 = e0 + 1;
    h_ = e1 >> 7; l_ = (e1 >> 5) & 3; d_ = e1 & 31;
    *(float*)(smem + QLOFF + (h_ * 132 + l_ * 33 + d_) * 4) = lv.y;
  }
  __syncthreads();

  // ---------------- phase 1: GEMM Y = W @ X, barrier-free ----------------
  {
    const unsigned char* Bb = smem + fm * 528 + quad * 16;
    const unsigned short* Ap = Wb + wv * 48 * 512 + lane * 8;  // wave stripe base
#pragma unroll
    for (int kt = 0; kt < 8; ++kt) {
      short8 bfrag[4];
#pragma unroll
      for (int j = 0; j < 4; ++j)
        bfrag[j] = *(const short8*)(Bb + j * 8448 + kt * 64);
#pragma unroll
      for (int i = 0; i < 6; ++i) {
        const short8 afrag = *(const short8*)(Ap + (i * 8 + kt) * 512);
#pragma unroll
        for (int j = 0; j < 4; ++j)
          acc[i][j] = __builtin_amdgcn_mfma_f32_16x16x32_bf16(afrag, bfrag[j], acc[i][j], 0, 0, 0);
      }
    }
  }
  __syncthreads();   // Bl dead after this; E overlays it

  // ---------------- epilogue setup ----------------
  float biasr[6][4];
#pragma unroll
  for (int i = 0; i < 6; ++i)
#pragma unroll
    for (int r = 0; r < 4; ++r) {
      const int row = wv * 96 + i * 16 + quad * 4 + r;
      biasr[i][r] = (row < 512) ? enc_b[row] : dec_b[row - 512];
    }

#pragma unroll
  for (int hf = 0; hf < 2; ++hf) {
    // ---- write E (enc rows, +bias), bf16 (k,v) pair-packed u32, swizzled ----
#pragma unroll
    for (int i = 0; i < 6; ++i) {
      const int row0 = wv * 96 + i * 16 + quad * 4;
      if (row0 < 512) {
#pragma unroll
        for (int jj = 0; jj < 2; ++jj) {
          const int col = jj * 16 + fm;  // 0..31 within half
#pragma unroll
          for (int r2 = 0; r2 < 2; ++r2) {
            const int row = row0 + r2 * 2;               // even -> k at lo, v at hi
            const float v0 = acc[i][hf * 2 + jj][r2 * 2]     + biasr[i][r2 * 2];
            const float v1 = acc[i][hf * 2 + jj][r2 * 2 + 1] + biasr[i][r2 * 2 + 1];
            const int h_ = row >> 6, d_ = (row & 63) >> 1;
            const int word = col * 257 + h_ * 32 + ((d_ + 4 * h_) & 31);
            *(unsigned int*)(smem + word * 4) = pack2bf(v0, v1);
          }
        }
      }
    }
    __syncthreads();

    // ---- attention 1: wave <-> patch, ALL 64 lanes: (cc, hh, ll) ----
    {
      const int cc = lane >> 5;         // half-wave: which col pair
      const int hh = (lane >> 2) & 7;
      const int ll = lane & 3;
      const unsigned int* Ew = (const unsigned int*)smem;
      const float* QLb = (const float*)(smem + QLOFF) + hh * 132 + ll * 33;
      const int cb = wv * 4;
      const unsigned int* EcA = Ew + (cb + cc * 2) * 257;
      const unsigned int* EcB = EcA + 257;
      float s0 = 0.f, s1 = 0.f;
#pragma unroll 8
      for (int d = 0; d < 32; ++d) {
        const float qd = QLb[d];
        const int wb_ = hh * 32 + ((d + 4 * hh) & 31);
        s0 += qd * bf2f((unsigned short)EcA[wb_]);
        s1 += qd * bf2f((unsigned short)EcB[wb_]);
      }
      const float sp0 = __shfl_xor(s0, 32);
      const float sp1 = __shfl_xor(s1, 32);
      const float sA = cc ? sp0 : s0;   // col cb+0
      const float sB = cc ? sp1 : s1;   // col cb+1
      const float sC = cc ? s0 : sp0;   // col cb+2
      const float sD = cc ? s1 : sp1;   // col cb+3
      const float mx = fmaxf(fmaxf(sA, sB), fmaxf(sC, sD));
      const float eA = __expf(sA - mx), eB = __expf(sB - mx);
      const float eC = __expf(sC - mx), eD = __expf(sD - mx);
      const float inv = 1.f / (eA + eB + eC + eD);
      const float a0 = eA * inv, a1 = eB * inv, a2_ = eC * inv, a3 = eD * inv;
      // each half-wave produces 16 of the 32 d-values
      unsigned char* LTb = smem + LTOFF + wv * 2112 + ll * 528 + hh * 64 + cc * 32;
#pragma unroll
      for (int d2 = 0; d2 < 8; ++d2) {
        unsigned int pk = 0;
#pragma unroll
        for (int dd = 0; dd < 2; ++dd) {
          const int d = cc * 16 + d2 * 2 + dd;
          const float qd = QLb[d];
          const int wb_ = hh * 32 + ((d + 4 * hh) & 31);
          const unsigned int kv0 = Ew[(cb + 0) * 257 + wb_];
          const unsigned int kv1 = Ew[(cb + 1) * 257 + wb_];
          const unsigned int kv2 = Ew[(cb + 2) * 257 + wb_];
          const unsigned int kv3 = Ew[(cb + 3) * 257 + wb_];
          const float lv = qd + a0 * bf2f((unsigned short)(kv0 >> 16))
                              + a1 * bf2f((unsigned short)(kv1 >> 16))
                              + a2_ * bf2f((unsigned short)(kv2 >> 16))
                              + a3 * bf2f((unsigned short)(kv3 >> 16));
          pk |= ((unsigned int)f2bf(lv)) << (16 * dd);
        }
        *(unsigned int*)(LTb + d2 * 4) = pk;
      }
    }
    __syncthreads();

    // ---- write D (dec rows, +bias) into E's dead space, u32-pair-packed ----
#pragma unroll
    for (int i = 0; i < 6; ++i) {
      const int row0 = wv * 96 + i * 16 + quad * 4;
      if (row0 >= 512) {
#pragma unroll
        for (int jj = 0; jj < 2; ++jj) {
          const int col = jj * 16 + fm;
#pragma unroll
          for (int r2 = 0; r2 < 2; ++r2) {
            const int cdx = row0 + r2 * 2 - 512;
            const float v0 = acc[i][hf * 2 + jj][r2 * 2]     + biasr[i][r2 * 2];
            const float v1 = acc[i][hf * 2 + jj][r2 * 2 + 1] + biasr[i][r2 * 2 + 1];
            *(unsigned int*)(smem + DOFF + col * 528 + cdx * 2) = pack2bf(v0, v1);
          }
        }
      }
    }
    // ---- spectral: in-place on LT; sin/cos once + angle-addition recurrence ----
    {
      unsigned char* LTp = smem + LTOFF + wv * 2112;
#pragma unroll
      for (int ii = 0; ii < 4; ++ii) {
        const int ic = ii * 64 + lane;  // channel i in [0,256)
        const float* wrp = weights + ic * 24;
        float wr_[24];
#pragma unroll
        for (int q2 = 0; q2 < 6; ++q2) {
          const float4 wq = *(const float4*)(wrp + q2 * 4);
          wr_[q2 * 4 + 0] = wq.x; wr_[q2 * 4 + 1] = wq.y;
          wr_[q2 * 4 + 2] = wq.z; wr_[q2 * 4 + 3] = wq.w;
        }
#pragma unroll
        for (int l2 = 0; l2 < 4; ++l2) {
          unsigned short* ps = (unsigned short*)(LTp + l2 * 528 + ic * 2);
          const float val = bf2f(*ps);
          const float th = val * 0.26179938779914946f;  // pi/12
          const float sn = __sinf(th), cs = __cosf(th);
          float av = wr_[12];  // m=0: cos term only
          float sm = sn, cm = cs;
#pragma unroll
          for (int mq = 1; mq <= 11; ++mq) {
            av += wr_[mq] * sm + wr_[12 + mq] * cm;
            if (mq < 11) {
              const float ns = sm * cs + cm * sn;
              cm = cm * cs - sm * sn;
              sm = ns;
            }
          }
          *ps = f2bf(av + val);
        }
      }
    }
    __syncthreads();

    // ---- attention 2 + xp + store: ALL 64 lanes: (cc, hh, pp) ----
    {
      const int cc = lane >> 5;         // half-wave: which 16-channel half
      const int hh = (lane >> 2) & 7;
      const int pp = lane & 3;
      const int col = wv * 4 + pp;
      const unsigned char* Db  = smem + DOFF + col * 528 + hh * 64 + cc * 32;
      const unsigned char* LTp = smem + LTOFF + wv * 2112;
      union u4b { uint4 q; unsigned short us[8]; };
      float dq[16];
#pragma unroll
      for (int c8 = 0; c8 < 2; ++c8) {
        u4b td; td.q = *(const uint4*)(Db + c8 * 16);
#pragma unroll
        for (int e = 0; e < 8; ++e) dq[c8 * 8 + e] = bf2f(td.us[e]);
      }
      float sc2[4];
#pragma unroll
      for (int l2 = 0; l2 < 4; ++l2) {
        float sa = 0.f;
#pragma unroll
        for (int c8 = 0; c8 < 2; ++c8) {
          u4b tl; tl.q = *(const uint4*)(LTp + l2 * 528 + hh * 64 + cc * 32 + c8 * 16);
#pragma unroll
          for (int e = 0; e < 8; ++e) sa += dq[c8 * 8 + e] * bf2f(tl.us[e]);
        }
        sc2[l2] = sa + __shfl_xor(sa, 32);   // symmetric -> identical across pair
      }
      const float mx2 = fmaxf(fmaxf(sc2[0], sc2[1]), fmaxf(sc2[2], sc2[3]));
      float ex[4];
#pragma unroll
      for (int l2 = 0; l2 < 4; ++l2) ex[l2] = __expf(sc2[l2] - mx2);
      const float inv2 = 1.f / (ex[0] + ex[1] + ex[2] + ex[3]);
      float aw[4];
#pragma unroll
      for (int l2 = 0; l2 < 4; ++l2) aw[l2] = ex[l2] * inv2;

      const int hpf = (blockIdx.x & 63) * 16 + hf * 8 + wv;  // Hp index
      const int hg  = h0 + hf * 32 + wv * 4 + pp;            // h index
      float* ob = out + bb * 1048576 + pp * 262144 + hpf * 256 + hh * 32 + cc * 16;
      const float* xc = x + bb * 1048576 + (hh * 32 + cc * 16) * 4096 + hg;
#pragma unroll
      for (int c8 = 0; c8 < 2; ++c8) {
        float ov[8];
#pragma unroll
        for (int e = 0; e < 8; ++e) ov[e] = 0.f;
#pragma unroll
        for (int l2 = 0; l2 < 4; ++l2) {
          u4b tl; tl.q = *(const uint4*)(LTp + l2 * 528 + hh * 64 + cc * 32 + c8 * 16);
#pragma unroll
          for (int e = 0; e < 8; ++e) ov[e] += aw[l2] * bf2f(tl.us[e]);
        }
#pragma unroll
        for (int e = 0; e < 8; ++e) ov[e] += xc[(c8 * 8 + e) * 4096];
        *(float4*)(ob + c8 * 8)     = make_float4(ov[0], ov[1], ov[2], ov[3]);
        *(float4*)(ob + c8 * 8 + 4) = make_float4(ov[4], ov[5], ov[6], ov[7]);
      }
    }
    __syncthreads();
  }
}

extern "C" void kernel_launch(void* const* d_in, const int* in_sizes, int n_in,
                              void* d_out, int out_size, void* d_ws, size_t ws_size,
                              hipStream_t stream) {
  const float* x       = (const float*)d_in[0];
  const float* weights = (const float*)d_in[1];
  const float* latent  = (const float*)d_in[2];
  const float* enc_w   = (const float*)d_in[3];
  const float* enc_b   = (const float*)d_in[4];
  const float* dec_w   = (const float*)d_in[5];
  const float* dec_b   = (const float*)d_in[6];
  unsigned short* Wb   = (unsigned short*)d_ws;  // 768*256 bf16 = 384 KB (frag order)
  float* outp          = (float*)d_out;

  wconv_kernel<<<96, 256, 0, stream>>>(enc_w, dec_w, Wb);
  nsb_kernel<<<2048, 512, 0, stream>>>(x, weights, latent, enc_b, dec_b, Wb, outp);
}

// Round 2
// 473.529 us; speedup vs baseline: 1.2581x; 1.2581x over previous
//
#include <hip/hip_runtime.h>

// NeuralSpectralBlock1d on MI355X (gfx950)
// B=32, C=256, H=4096, PATCH=4, HEAD=8, DH=32, NT=4, NB=12
// Fused design (v3 = v2 structure, spill + bank-conflict fixes):
//   wconv_kernel: enc_w(512x256) ++ dec_w(256x256) -> bf16 Wb in d_ws,
//                 laid out in MFMA *fragment order*:
//                 block(m16,kt) = 1024B: [quad][fm][8 bf16], so a lane's
//                 A-frag is one coalesced 16B global load (L2-resident).
//   nsb_kernel:   grid 2048 = 32 b * 64 col-chunks; block 512 thr (8 waves)
//     stage:   X tile (256k x 64col) -> LDS bf16 transposed, ONCE; + QL; 1 barrier
//     phase 1: Y(768x64) = Wb @ X via mfma_f32_16x16x32_bf16, BARRIER-FREE
//              (A-frags straight from global Wb; B-frags from LDS)
//              wave w owns rows [w*96, w*96+96): acc[6][4] f32x4 (96 VGPRs)
//     phase 2: two halves of 32 cols (8 patches); wave <-> patch; attn1/attn2
//              use ALL 64 lanes (half-waves split cols/channels, scores
//              exchanged via __shfl_xor(.,32)); E/D writes u32-pair-packed.
//
// v3 fixes vs v2 (both counter-driven):
//   - __launch_bounds__(512): v2's (512,4) made the compiler cap VGPR at 64
//     -> acc[6][4] spilled to scratch -> +1.1 GB HBM traffic. Plain form
//     compiled to 128 VGPR (2 blocks/CU) in the 385us baseline.
//   - Bl row stride 528 -> 536 B (134 dwords, 6*fm mod 32 = 16 bank starts)
//     and B-frag reads as 2x uint2 (8B-aligned). v2's 528 (132 dwords ==
//     4 mod 32) put fm-rows on only 8 bank starts -> ~8-way ds_read_b128
//     conflicts (+1.2e7 SQ_LDS_BANK_CONFLICT).
//
// LDS map (54016 B):
//   stage/GEMM: Bl [0,34304)     64 cols * 536 B (256 bf16 k + pad)
//   epilog:     E  [0,32896)     32 cols * 1028 B; (k,v) pair word, d+4h swizzle
//               D  [0,16896)     32 cols * 528 B  (written after attn1; E dead)
//               LT [32896,49792) 8 patches * 4 l * 528 B
//               QL [49792,54016) latent fp32, [h][l][33] padded
//   (Bl overlaps E/D/LT but is dead before any of them is written.)

typedef __attribute__((ext_vector_type(8))) short short8;
typedef __attribute__((ext_vector_type(4))) float f32x4;

#define BSTRIDE 536
#define DOFF 0
#define LTOFF 32896
#define QLOFF 49792

__device__ __forceinline__ unsigned short f2bf(float f) {
  union { float f; unsigned int u; } c; c.f = f;
  unsigned int u = c.u + 0x7FFFu + ((c.u >> 16) & 1u);
  return (unsigned short)(u >> 16);
}
__device__ __forceinline__ float bf2f(unsigned short s) {
  union { unsigned int u; float f; } c; c.u = ((unsigned int)s) << 16;
  return c.f;
}
__device__ __forceinline__ unsigned int pack2bf(float lo, float hi) {
  return (unsigned int)f2bf(lo) | ((unsigned int)f2bf(hi) << 16);
}

// Wb fragment layout: element index = ((m16*8 + kt)*64 + quad*16 + fm)*8 + j
// source: W[row = m16*16 + fm][k = kt*32 + quad*8 + j]
__global__ void wconv_kernel(const float* __restrict__ enc_w,
                             const float* __restrict__ dec_w,
                             unsigned short* __restrict__ Wb) {
  const int g   = blockIdx.x * 256 + threadIdx.x;  // 96*256 = 24576 = 196608/8
  const int blk = g >> 6;        // m16*8 + kt
  const int lp  = g & 63;        // quad*16 + fm
  const int m16 = blk >> 3, kt = blk & 7;
  const int fm  = lp & 15, quad = lp >> 4;
  const int row = m16 * 16 + fm;
  const int k   = kt * 32 + quad * 8;
  const float* src = (row < 512) ? (enc_w + row * 256 + k)
                                 : (dec_w + (row - 512) * 256 + k);
  const float4 v0 = *(const float4*)(src);
  const float4 v1 = *(const float4*)(src + 4);
  ushort4 o0, o1;
  o0.x = f2bf(v0.x); o0.y = f2bf(v0.y); o0.z = f2bf(v0.z); o0.w = f2bf(v0.w);
  o1.x = f2bf(v1.x); o1.y = f2bf(v1.y); o1.z = f2bf(v1.z); o1.w = f2bf(v1.w);
  *(ushort4*)(Wb + g * 8)     = o0;
  *(ushort4*)(Wb + g * 8 + 4) = o1;
}

__global__ __launch_bounds__(512) void nsb_kernel(
    const float* __restrict__ x,
    const float* __restrict__ weights,
    const float* __restrict__ latent,
    const float* __restrict__ enc_b,
    const float* __restrict__ dec_b,
    const unsigned short* __restrict__ Wb,
    float* __restrict__ out)
{
  __shared__ __attribute__((aligned(16))) unsigned char smem[54016];
  const int t    = threadIdx.x;
  const int wv   = t >> 6;       // wave 0..7
  const int lane = t & 63;
  const int fm   = lane & 15;    // mfma m/n index
  const int quad = lane >> 4;    // mfma k-group / row-quad
  const int bb   = blockIdx.x >> 6;          // batch
  const int h0   = (blockIdx.x & 63) << 6;   // column base in H

  f32x4 acc[6][4];
#pragma unroll
  for (int i = 0; i < 6; ++i)
#pragma unroll
    for (int j = 0; j < 4; ++j)
      acc[i][j] = f32x4{0.f, 0.f, 0.f, 0.f};

  // ---------------- stage: full X tile -> Bl (bf16, transposed) + QL ----------------
  {
    const int cB = t >> 4;          // 0..31
    const int h4 = (t & 15) << 2;   // 0..60
    const float* xb = x + (bb * 256 + cB) * 4096 + h0 + h4;
#pragma unroll
    for (int rd = 0; rd < 8; ++rd) {
      const float4 xv = *(const float4*)(xb + rd * 32 * 4096);
      const int c2 = (rd * 32 + cB) * 2;
      *(unsigned short*)(smem + (h4 + 0) * BSTRIDE + c2) = f2bf(xv.x);
      *(unsigned short*)(smem + (h4 + 1) * BSTRIDE + c2) = f2bf(xv.y);
      *(unsigned short*)(smem + (h4 + 2) * BSTRIDE + c2) = f2bf(xv.z);
      *(unsigned short*)(smem + (h4 + 3) * BSTRIDE + c2) = f2bf(xv.w);
    }
  }
  {
    const int e0 = t * 2;
    const float2 lv = *(const float2*)(latent + e0);
    int h_ = e0 >> 7, l_ = (e0 >> 5) & 3, d_ = e0 & 31;
    *(float*)(smem + QLOFF + (h_ * 132 + l_ * 33 + d_) * 4) = lv.x;
    const int e1 = e0 + 1;
    h_ = e1 >> 7; l_ = (e1 >> 5) & 3; d_ = e1 & 31;
    *(float*)(smem + QLOFF + (h_ * 132 + l_ * 33 + d_) * 4) = lv.y;
  }
  __syncthreads();

  // ---------------- phase 1: GEMM Y = W @ X, barrier-free ----------------
  {
    const unsigned char* Bb = smem + fm * BSTRIDE + quad * 16;
    const unsigned short* Ap = Wb + wv * 48 * 512 + lane * 8;  // wave stripe base
#pragma unroll
    for (int kt = 0; kt < 8; ++kt) {
      short8 bfrag[4];
#pragma unroll
      for (int j = 0; j < 4; ++j) {
        const unsigned char* p = Bb + j * 16 * BSTRIDE + kt * 64;
        union { short8 s; uint2 u[2]; } tb;
        tb.u[0] = *(const uint2*)(p);
        tb.u[1] = *(const uint2*)(p + 8);
        bfrag[j] = tb.s;
      }
#pragma unroll
      for (int i = 0; i < 6; ++i) {
        const short8 afrag = *(const short8*)(Ap + (i * 8 + kt) * 512);
#pragma unroll
        for (int j = 0; j < 4; ++j)
          acc[i][j] = __builtin_amdgcn_mfma_f32_16x16x32_bf16(afrag, bfrag[j], acc[i][j], 0, 0, 0);
      }
    }
  }
  __syncthreads();   // Bl dead after this; E overlays it

  // ---------------- epilogue setup ----------------
  float biasr[6][4];
#pragma unroll
  for (int i = 0; i < 6; ++i)
#pragma unroll
    for (int r = 0; r < 4; ++r) {
      const int row = wv * 96 + i * 16 + quad * 4 + r;
      biasr[i][r] = (row < 512) ? enc_b[row] : dec_b[row - 512];
    }

#pragma unroll
  for (int hf = 0; hf < 2; ++hf) {
    // ---- write E (enc rows, +bias), bf16 (k,v) pair-packed u32, swizzled ----
#pragma unroll
    for (int i = 0; i < 6; ++i) {
      const int row0 = wv * 96 + i * 16 + quad * 4;
      if (row0 < 512) {
#pragma unroll
        for (int jj = 0; jj < 2; ++jj) {
          const int col = jj * 16 + fm;  // 0..31 within half
#pragma unroll
          for (int r2 = 0; r2 < 2; ++r2) {
            const int row = row0 + r2 * 2;               // even -> k at lo, v at hi
            const float v0 = acc[i][hf * 2 + jj][r2 * 2]     + biasr[i][r2 * 2];
            const float v1 = acc[i][hf * 2 + jj][r2 * 2 + 1] + biasr[i][r2 * 2 + 1];
            const int h_ = row >> 6, d_ = (row & 63) >> 1;
            const int word = col * 257 + h_ * 32 + ((d_ + 4 * h_) & 31);
            *(unsigned int*)(smem + word * 4) = pack2bf(v0, v1);
          }
        }
      }
    }
    __syncthreads();

    // ---- attention 1: wave <-> patch, ALL 64 lanes: (cc, hh, ll) ----
    {
      const int cc = lane >> 5;         // half-wave: which col pair
      const int hh = (lane >> 2) & 7;
      const int ll = lane & 3;
      const unsigned int* Ew = (const unsigned int*)smem;
      const float* QLb = (const float*)(smem + QLOFF) + hh * 132 + ll * 33;
      const int cb = wv * 4;
      const unsigned int* EcA = Ew + (cb + cc * 2) * 257;
      const unsigned int* EcB = EcA + 257;
      float s0 = 0.f, s1 = 0.f;
#pragma unroll 8
      for (int d = 0; d < 32; ++d) {
        const float qd = QLb[d];
        const int wb_ = hh * 32 + ((d + 4 * hh) & 31);
        s0 += qd * bf2f((unsigned short)EcA[wb_]);
        s1 += qd * bf2f((unsigned short)EcB[wb_]);
      }
      const float sp0 = __shfl_xor(s0, 32);
      const float sp1 = __shfl_xor(s1, 32);
      const float sA = cc ? sp0 : s0;   // col cb+0
      const float sB = cc ? sp1 : s1;   // col cb+1
      const float sC = cc ? s0 : sp0;   // col cb+2
      const float sD = cc ? s1 : sp1;   // col cb+3
      const float mx = fmaxf(fmaxf(sA, sB), fmaxf(sC, sD));
      const float eA = __expf(sA - mx), eB = __expf(sB - mx);
      const float eC = __expf(sC - mx), eD = __expf(sD - mx);
      const float inv = 1.f / (eA + eB + eC + eD);
      const float a0 = eA * inv, a1 = eB * inv, a2_ = eC * inv, a3 = eD * inv;
      // each half-wave produces 16 of the 32 d-values
      unsigned char* LTb = smem + LTOFF + wv * 2112 + ll * 528 + hh * 64 + cc * 32;
#pragma unroll
      for (int d2 = 0; d2 < 8; ++d2) {
        unsigned int pk = 0;
#pragma unroll
        for (int dd = 0; dd < 2; ++dd) {
          const int d = cc * 16 + d2 * 2 + dd;
          const float qd = QLb[d];
          const int wb_ = hh * 32 + ((d + 4 * hh) & 31);
          const unsigned int kv0 = Ew[(cb + 0) * 257 + wb_];
          const unsigned int kv1 = Ew[(cb + 1) * 257 + wb_];
          const unsigned int kv2 = Ew[(cb + 2) * 257 + wb_];
          const unsigned int kv3 = Ew[(cb + 3) * 257 + wb_];
          const float lv = qd + a0 * bf2f((unsigned short)(kv0 >> 16))
                              + a1 * bf2f((unsigned short)(kv1 >> 16))
                              + a2_ * bf2f((unsigned short)(kv2 >> 16))
                              + a3 * bf2f((unsigned short)(kv3 >> 16));
          pk |= ((unsigned int)f2bf(lv)) << (16 * dd);
        }
        *(unsigned int*)(LTb + d2 * 4) = pk;
      }
    }
    __syncthreads();

    // ---- write D (dec rows, +bias) into E's dead space, u32-pair-packed ----
#pragma unroll
    for (int i = 0; i < 6; ++i) {
      const int row0 = wv * 96 + i * 16 + quad * 4;
      if (row0 >= 512) {
#pragma unroll
        for (int jj = 0; jj < 2; ++jj) {
          const int col = jj * 16 + fm;
#pragma unroll
          for (int r2 = 0; r2 < 2; ++r2) {
            const int cdx = row0 + r2 * 2 - 512;
            const float v0 = acc[i][hf * 2 + jj][r2 * 2]     + biasr[i][r2 * 2];
            const float v1 = acc[i][hf * 2 + jj][r2 * 2 + 1] + biasr[i][r2 * 2 + 1];
            *(unsigned int*)(smem + DOFF + col * 528 + cdx * 2) = pack2bf(v0, v1);
          }
        }
      }
    }
    // ---- spectral: in-place on LT; sin/cos once + angle-addition recurrence ----
    {
      unsigned char* LTp = smem + LTOFF + wv * 2112;
#pragma unroll
      for (int ii = 0; ii < 4; ++ii) {
        const int ic = ii * 64 + lane;  // channel i in [0,256)
        const float* wrp = weights + ic * 24;
        float wr_[24];
#pragma unroll
        for (int q2 = 0; q2 < 6; ++q2) {
          const float4 wq = *(const float4*)(wrp + q2 * 4);
          wr_[q2 * 4 + 0] = wq.x; wr_[q2 * 4 + 1] = wq.y;
          wr_[q2 * 4 + 2] = wq.z; wr_[q2 * 4 + 3] = wq.w;
        }
#pragma unroll
        for (int l2 = 0; l2 < 4; ++l2) {
          unsigned short* ps = (unsigned short*)(LTp + l2 * 528 + ic * 2);
          const float val = bf2f(*ps);
          const float th = val * 0.26179938779914946f;  // pi/12
          const float sn = __sinf(th), cs = __cosf(th);
          float av = wr_[12];  // m=0: cos term only
          float sm = sn, cm = cs;
#pragma unroll
          for (int mq = 1; mq <= 11; ++mq) {
            av += wr_[mq] * sm + wr_[12 + mq] * cm;
            if (mq < 11) {
              const float ns = sm * cs + cm * sn;
              cm = cm * cs - sm * sn;
              sm = ns;
            }
          }
          *ps = f2bf(av + val);
        }
      }
    }
    __syncthreads();

    // ---- attention 2 + xp + store: ALL 64 lanes: (cc, hh, pp) ----
    {
      const int cc = lane >> 5;         // half-wave: which 16-channel half
      const int hh = (lane >> 2) & 7;
      const int pp = lane & 3;
      const int col = wv * 4 + pp;
      const unsigned char* Db  = smem + DOFF + col * 528 + hh * 64 + cc * 32;
      const unsigned char* LTp = smem + LTOFF + wv * 2112;
      union u4b { uint4 q; unsigned short us[8]; };
      float dq[16];
#pragma unroll
      for (int c8 = 0; c8 < 2; ++c8) {
        u4b td; td.q = *(const uint4*)(Db + c8 * 16);
#pragma unroll
        for (int e = 0; e < 8; ++e) dq[c8 * 8 + e] = bf2f(td.us[e]);
      }
      float sc2[4];
#pragma unroll
      for (int l2 = 0; l2 < 4; ++l2) {
        float sa = 0.f;
#pragma unroll
        for (int c8 = 0; c8 < 2; ++c8) {
          u4b tl; tl.q = *(const uint4*)(LTp + l2 * 528 + hh * 64 + cc * 32 + c8 * 16);
#pragma unroll
          for (int e = 0; e < 8; ++e) sa += dq[c8 * 8 + e] * bf2f(tl.us[e]);
        }
        sc2[l2] = sa + __shfl_xor(sa, 32);   // full 32-chan dot via pair exchange
      }
      const float mx2 = fmaxf(fmaxf(sc2[0], sc2[1]), fmaxf(sc2[2], sc2[3]));
      float ex[4];
#pragma unroll
      for (int l2 = 0; l2 < 4; ++l2) ex[l2] = __expf(sc2[l2] - mx2);
      const float inv2 = 1.f / (ex[0] + ex[1] + ex[2] + ex[3]);
      float aw[4];
#pragma unroll
      for (int l2 = 0; l2 < 4; ++l2) aw[l2] = ex[l2] * inv2;

      const int hpf = (blockIdx.x & 63) * 16 + hf * 8 + wv;  // Hp index
      const int hg  = h0 + hf * 32 + wv * 4 + pp;            // h index
      float* ob = out + bb * 1048576 + pp * 262144 + hpf * 256 + hh * 32 + cc * 16;
      const float* xc = x + bb * 1048576 + (hh * 32 + cc * 16) * 4096 + hg;
#pragma unroll
      for (int c8 = 0; c8 < 2; ++c8) {
        float ov[8];
#pragma unroll
        for (int e = 0; e < 8; ++e) ov[e] = 0.f;
#pragma unroll
        for (int l2 = 0; l2 < 4; ++l2) {
          u4b tl; tl.q = *(const uint4*)(LTp + l2 * 528 + hh * 64 + cc * 32 + c8 * 16);
#pragma unroll
          for (int e = 0; e < 8; ++e) ov[e] += aw[l2] * bf2f(tl.us[e]);
        }
#pragma unroll
        for (int e = 0; e < 8; ++e) ov[e] += xc[(c8 * 8 + e) * 4096];
        *(float4*)(ob + c8 * 8)     = make_float4(ov[0], ov[1], ov[2], ov[3]);
        *(float4*)(ob + c8 * 8 + 4) = make_float4(ov[4], ov[5], ov[6], ov[7]);
      }
    }
    __syncthreads();
  }
}

extern "C" void kernel_launch(void* const* d_in, const int* in_sizes, int n_in,
                              void* d_out, int out_size, void* d_ws, size_t ws_size,
                              hipStream_t stream) {
  const float* x       = (const float*)d_in[0];
  const float* weights = (const float*)d_in[1];
  const float* latent  = (const float*)d_in[2];
  const float* enc_w   = (const float*)d_in[3];
  const float* enc_b   = (const float*)d_in[4];
  const float* dec_w   = (const float*)d_in[5];
  const float* dec_b   = (const float*)d_in[6];
  unsigned short* Wb   = (unsigned short*)d_ws;  // 768*256 bf16 = 384 KB (frag order)
  float* outp          = (float*)d_out;

  wconv_kernel<<<96, 256, 0, stream>>>(enc_w, dec_w, Wb);
  nsb_kernel<<<2048, 512, 0, stream>>>(x, weights, latent, enc_b, dec_b, Wb, outp);
}